// Round 1
// baseline (48080.109 us; speedup 1.0000x reference)
//
#include <hip/hip_runtime.h>
#include <hip/hip_bf16.h>
#include <stdint.h>

typedef __attribute__((ext_vector_type(8))) short bf16x8;
typedef __attribute__((ext_vector_type(4))) float f32x4;

__device__ __forceinline__ unsigned short f2bf(float f) {
    union { float f; unsigned int u; } v; v.f = f;
    unsigned int u = v.u;
    return (unsigned short)((u + 0x7fffu + ((u >> 16) & 1u)) >> 16);  // RNE
}
__device__ __forceinline__ float bf2f(unsigned short b) {
    union { unsigned int u; float f; } v; v.u = ((unsigned int)b) << 16;
    return v.f;
}
__device__ __forceinline__ float blo(unsigned int u) {
    union { unsigned int u; float f; } v; v.u = u << 16; return v.f;
}
__device__ __forceinline__ float bhi(unsigned int u) {
    union { unsigned int u; float f; } v; v.u = u & 0xffff0000u; return v.f;
}

// ---------------- pack kernels (fp32 -> bf16, with K padding) ----------------

__global__ void pack_x_kernel(const float* __restrict__ x, unsigned short* __restrict__ xp,
                              int M, int K, int Kp) {
    int total = M * Kp;
    for (int idx = blockIdx.x * blockDim.x + threadIdx.x; idx < total;
         idx += gridDim.x * blockDim.x) {
        int r = idx / Kp, k = idx - r * Kp;
        xp[idx] = (k < K) ? f2bf(x[(size_t)r * K + k]) : (unsigned short)0;
    }
}

// packs 4 gate matrices (each 512 x K fp32) into (2048 x Kp) bf16, row n = gate*512+j
__global__ void pack_w_kernel(const float* __restrict__ Wf, const float* __restrict__ Wi,
                              const float* __restrict__ Wo, const float* __restrict__ Wc,
                              unsigned short* __restrict__ out, int K, int Kp) {
    int total = 2048 * Kp;
    for (int idx = blockIdx.x * blockDim.x + threadIdx.x; idx < total;
         idx += gridDim.x * blockDim.x) {
        int n = idx / Kp, k = idx - n * Kp;
        int gate = n >> 9, j = n & 511;
        const float* W = (gate == 0) ? Wf : (gate == 1) ? Wi : (gate == 2) ? Wo : Wc;
        out[idx] = (k < K) ? f2bf(W[(size_t)j * K + k]) : (unsigned short)0;
    }
}

// ---------------- gate GEMM: G[row, n] = sum_k A[row,k]*B[n,k] + bias ----------------
// A: M x Kp bf16 row-major.  B: 2048 x Kp bf16 row-major (i.e. B^T layout, K contiguous).
// 64x64 tile, 4 waves, mfma_f32_16x16x32_bf16. M % 64 == 0, Kp % 32 == 0, N = 2048.

__global__ __launch_bounds__(256) void gemm_gates(
    const unsigned short* __restrict__ A, const unsigned short* __restrict__ Bm,
    const float* __restrict__ bF, const float* __restrict__ bI,
    const float* __restrict__ bO, const float* __restrict__ bC,
    unsigned short* __restrict__ G, int Kp) {
    __shared__ unsigned short Alds[64][32];
    __shared__ unsigned short Blds[64][32];
    const int tid = threadIdx.x;
    const int m0 = blockIdx.x * 64;
    const int n0 = blockIdx.y * 64;
    const int w = tid >> 6, l = tid & 63;
    const int lr = l & 15, lk = (l >> 4) * 8;
    const int ldrow = tid >> 2;
    const int ldk = (tid & 3) * 8;
    const unsigned short* Aptr = A + (size_t)(m0 + ldrow) * Kp + ldk;
    const unsigned short* Bptr = Bm + (size_t)(n0 + ldrow) * Kp + ldk;

    f32x4 zero = {0.f, 0.f, 0.f, 0.f};
    f32x4 acc0 = zero, acc1 = zero, acc2 = zero, acc3 = zero;

    for (int k0 = 0; k0 < Kp; k0 += 32) {
        *(uint4*)&Alds[ldrow][ldk] = *(const uint4*)(Aptr + k0);
        *(uint4*)&Blds[ldrow][ldk] = *(const uint4*)(Bptr + k0);
        __syncthreads();
        bf16x8 a = *(const bf16x8*)&Alds[w * 16 + lr][lk];
        bf16x8 b0 = *(const bf16x8*)&Blds[0 * 16 + lr][lk];
        bf16x8 b1 = *(const bf16x8*)&Blds[1 * 16 + lr][lk];
        bf16x8 b2 = *(const bf16x8*)&Blds[2 * 16 + lr][lk];
        bf16x8 b3 = *(const bf16x8*)&Blds[3 * 16 + lr][lk];
        acc0 = __builtin_amdgcn_mfma_f32_16x16x32_bf16(a, b0, acc0, 0, 0, 0);
        acc1 = __builtin_amdgcn_mfma_f32_16x16x32_bf16(a, b1, acc1, 0, 0, 0);
        acc2 = __builtin_amdgcn_mfma_f32_16x16x32_bf16(a, b2, acc2, 0, 0, 0);
        acc3 = __builtin_amdgcn_mfma_f32_16x16x32_bf16(a, b3, acc3, 0, 0, 0);
        __syncthreads();
    }
    const int gate = n0 >> 9;
    const float* bias = (gate == 0) ? bF : (gate == 1) ? bI : (gate == 2) ? bO : bC;
    f32x4 accs[4] = {acc0, acc1, acc2, acc3};
#pragma unroll
    for (int c = 0; c < 4; ++c) {
        int col = n0 + c * 16 + lr;
        float bv = bias[col & 511];
#pragma unroll
        for (int r = 0; r < 4; ++r) {
            int row = m0 + w * 16 + (l >> 4) * 4 + r;
            G[(size_t)row * 2048 + col] = f2bf(accs[c][r] + bv);
        }
    }
}

// ---------------- persistent recurrence ----------------
// 256 wgs x 1024 thr. Lane L = bx>>3 (16 fwd + 16 bwd), sub-group g8 = bx&7 owns
// h-dims [g8*64, g8*64+64) x 4 gates. U-slice (256 rows x 512 k bf16) lives in VGPRs.
// Per thread: wave w holds k-chunk [w*32,w*32+32), lane l holds rows 4l..4l+3.

__global__ __launch_bounds__(1024, 4) void lstm_rec(
    const unsigned short* __restrict__ U,  // 2048 x 512 bf16
    const unsigned short* __restrict__ G,  // (T*16) x 2048 bf16
    unsigned short* __restrict__ y_bf,     // layer0 out (T*16 x 1024 bf16) or null
    float* __restrict__ y_f32,             // layer1 out (d_out) or null
    float* h_buf,                          // [2][32][512] fp32
    unsigned int* bar,                     // [32]
    int T) {
    const int tid = threadIdx.x;
    const int w = tid >> 6, l = tid & 63;
    const int bx = blockIdx.x;
    const int L = bx >> 3;
    const int g8 = bx & 7;
    const int j_base = g8 * 64;
    const int b = L & 15;
    const bool fwd = (L < 16);

    __shared__ float h_lds[512];
    __shared__ float part_lds[256][17];
    __shared__ float preact[256];

    // load register-resident weights (once)
    uint4 uw[4][4];
#pragma unroll
    for (int ri = 0; ri < 4; ++ri) {
        int nl = l * 4 + ri;
        int gate = nl >> 6, jl = nl & 63;
        const unsigned short* src = U + (size_t)(gate * 512 + j_base + jl) * 512 + w * 32;
#pragma unroll
        for (int q = 0; q < 4; ++q) uw[ri][q] = ((const uint4*)src)[q];
    }

    if (tid < 512) h_lds[tid] = 0.0f;
    float c_reg = 0.0f;
    __syncthreads();

    for (int s = 0; s < T; ++s) {
        // ---- partial dot products from register weights ----
        float p0 = 0.f, p1 = 0.f, p2 = 0.f, p3 = 0.f;
        const float* hv = &h_lds[w * 32];
#pragma unroll
        for (int q = 0; q < 4; ++q) {
            float4 ha = ((const float4*)hv)[2 * q];
            float4 hb = ((const float4*)hv)[2 * q + 1];
            {
                uint4 u = uw[0][q];
                p0 += blo(u.x) * ha.x + bhi(u.x) * ha.y + blo(u.y) * ha.z + bhi(u.y) * ha.w;
                p0 += blo(u.z) * hb.x + bhi(u.z) * hb.y + blo(u.w) * hb.z + bhi(u.w) * hb.w;
            }
            {
                uint4 u = uw[1][q];
                p1 += blo(u.x) * ha.x + bhi(u.x) * ha.y + blo(u.y) * ha.z + bhi(u.y) * ha.w;
                p1 += blo(u.z) * hb.x + bhi(u.z) * hb.y + blo(u.w) * hb.z + bhi(u.w) * hb.w;
            }
            {
                uint4 u = uw[2][q];
                p2 += blo(u.x) * ha.x + bhi(u.x) * ha.y + blo(u.y) * ha.z + bhi(u.y) * ha.w;
                p2 += blo(u.z) * hb.x + bhi(u.z) * hb.y + blo(u.w) * hb.z + bhi(u.w) * hb.w;
            }
            {
                uint4 u = uw[3][q];
                p3 += blo(u.x) * ha.x + bhi(u.x) * ha.y + blo(u.y) * ha.z + bhi(u.y) * ha.w;
                p3 += blo(u.z) * hb.x + bhi(u.z) * hb.y + blo(u.w) * hb.z + bhi(u.w) * hb.w;
            }
        }
        part_lds[l * 4 + 0][w] = p0;
        part_lds[l * 4 + 1][w] = p1;
        part_lds[l * 4 + 2][w] = p2;
        part_lds[l * 4 + 3][w] = p3;
        __syncthreads();

        const int t_idx = fwd ? s : (T - 1 - s);

        // ---- reduce 16 k-chunks, add gate projection ----
        if (tid < 256) {
            float sum = 0.f;
#pragma unroll
            for (int q = 0; q < 16; ++q) sum += part_lds[tid][q];
            int gate = tid >> 6, jl = tid & 63;
            sum += bf2f(G[(size_t)(t_idx * 16 + b) * 2048 + gate * 512 + j_base + jl]);
            preact[tid] = sum;
        }
        __syncthreads();

        // ---- pointwise gates + state update (64 finalizer threads own c) ----
        if (tid < 64) {
            float gf = preact[tid], gi = preact[64 + tid];
            float go = preact[128 + tid], gc = preact[192 + tid];
            float ft = 1.f / (1.f + __expf(-gf));
            float it = 1.f / (1.f + __expf(-gi));
            float ot = 1.f / (1.f + __expf(-go));
            float cn = it * tanhf(gc) + ft * c_reg;
            c_reg = cn;
            float hn = ot * tanhf(cn);
            int p = (s + 1) & 1;
            __hip_atomic_store(&h_buf[(size_t)p * 32 * 512 + L * 512 + j_base + tid], hn,
                               __ATOMIC_RELAXED, __HIP_MEMORY_SCOPE_AGENT);
            int orow = t_idx * 16 + b;
            int ocol = (fwd ? 0 : 512) + j_base + tid;
            if (y_bf)
                y_bf[(size_t)orow * 1024 + ocol] = f2bf(hn);
            else
                y_f32[(size_t)orow * 1024 + ocol] = hn;
        }
        __syncthreads();

        // ---- 8-wg per-lane barrier ----
        if (tid == 0) {
            __hip_atomic_fetch_add(&bar[L], 1u, __ATOMIC_RELEASE, __HIP_MEMORY_SCOPE_AGENT);
            unsigned int target = 8u * (unsigned int)(s + 1);
            while (__hip_atomic_load(&bar[L], __ATOMIC_ACQUIRE, __HIP_MEMORY_SCOPE_AGENT) <
                   target)
                __builtin_amdgcn_s_sleep(1);
        }
        __syncthreads();

        // ---- gather full h for next step ----
        {
            int p = (s + 1) & 1;
            if (tid < 512)
                h_lds[tid] = __hip_atomic_load(&h_buf[(size_t)p * 32 * 512 + L * 512 + tid],
                                               __ATOMIC_RELAXED, __HIP_MEMORY_SCOPE_AGENT);
        }
        __syncthreads();
    }
}

// ---------------- host ----------------

extern "C" void kernel_launch(void* const* d_in, const int* in_sizes, int n_in,
                              void* d_out, int out_size, void* d_ws, size_t ws_size,
                              hipStream_t stream) {
    (void)in_sizes; (void)n_in; (void)out_size; (void)ws_size;
    const int T = 1000, Bb = 16, M = T * Bb;
    const int K0 = 440, K0p = 448, K1 = 1024;

    char* ws = (char*)d_ws;
    size_t off = 0;
    auto alloc = [&](size_t bytes) -> void* {
        void* p = ws + off;
        off += (bytes + 255) & ~(size_t)255;
        return p;
    };
    unsigned short* G  = (unsigned short*)alloc((size_t)M * 2048 * 2);   // 65.5 MB
    unsigned short* xp = (unsigned short*)alloc((size_t)M * K0p * 2);    // 14.3 MB
    unsigned short* W0 = (unsigned short*)alloc((size_t)2048 * K0p * 2);
    unsigned short* W1 = (unsigned short*)alloc((size_t)2048 * K1 * 2);
    unsigned short* U0 = (unsigned short*)alloc((size_t)2048 * 512 * 2);
    unsigned short* U1 = (unsigned short*)alloc((size_t)2048 * 512 * 2);
    unsigned short* y0 = (unsigned short*)alloc((size_t)M * 1024 * 2);   // 32.8 MB
    float* h_buf       = (float*)alloc((size_t)2 * 32 * 512 * 4);
    unsigned int* bar  = (unsigned int*)alloc(64 * 4);

    const float* x = (const float*)d_in[0];
    // d_in: 1 Wf0, 2 bf0, 3 Uf0, 4 Wi0, 5 bi0, 6 Ui0, 7 Wo0, 8 bo0, 9 Uo0,
    //       10 Wc0, 11 bc0, 12 Uc0, 13 Wf1, 14 bf1, 15 Uf1, 16 Wi1, 17 bi1,
    //       18 Ui1, 19 Wo1, 20 bo1, 21 Uo1, 22 Wc1, 23 bc1, 24 Uc1

    hipMemsetAsync(bar, 0, 64 * 4, stream);

    pack_x_kernel<<<2048, 256, 0, stream>>>(x, xp, M, K0, K0p);
    pack_w_kernel<<<1024, 256, 0, stream>>>((const float*)d_in[1], (const float*)d_in[4],
                                            (const float*)d_in[7], (const float*)d_in[10],
                                            W0, K0, K0p);
    pack_w_kernel<<<1024, 256, 0, stream>>>((const float*)d_in[3], (const float*)d_in[6],
                                            (const float*)d_in[9], (const float*)d_in[12],
                                            U0, 512, 512);
    pack_w_kernel<<<1024, 256, 0, stream>>>((const float*)d_in[13], (const float*)d_in[16],
                                            (const float*)d_in[19], (const float*)d_in[22],
                                            W1, K1, K1);
    pack_w_kernel<<<1024, 256, 0, stream>>>((const float*)d_in[15], (const float*)d_in[18],
                                            (const float*)d_in[21], (const float*)d_in[24],
                                            U1, 512, 512);

    dim3 blk(256);
    dim3 g0(M / 64, 2048 / 64);
    // layer 0 gates
    gemm_gates<<<g0, blk, 0, stream>>>(xp, W0, (const float*)d_in[2], (const float*)d_in[5],
                                       (const float*)d_in[8], (const float*)d_in[11], G, K0p);
    // layer 0 recurrence -> y0 (bf16)
    lstm_rec<<<256, 1024, 0, stream>>>(U0, G, y0, nullptr, h_buf, bar, T);
    // layer 1 gates
    gemm_gates<<<g0, blk, 0, stream>>>(y0, W1, (const float*)d_in[14], (const float*)d_in[17],
                                       (const float*)d_in[20], (const float*)d_in[23], G, K1);
    // layer 1 recurrence -> d_out (fp32)
    lstm_rec<<<256, 1024, 0, stream>>>(U1, G, nullptr, (float*)d_out, h_buf, bar + 32, T);
}

// Round 2
// 24552.985 us; speedup vs baseline: 1.9582x; 1.9582x over previous
//
#include <hip/hip_runtime.h>
#include <hip/hip_bf16.h>
#include <stdint.h>

// Round 2: recurrence restructured as 32-wg MFMA with LDS-resident weights,
// per-wave flag barrier (padded lines), IF$-scope h exchange in fragment layout,
// quad-shuffle gate combine (zero __syncthreads in the time loop), G prefetch.

typedef __attribute__((ext_vector_type(8))) short bf16x8;
typedef __attribute__((ext_vector_type(4))) float f32x4;

__device__ __forceinline__ unsigned short f2bf(float f) {
    union { float f; unsigned int u; } v; v.f = f;
    unsigned int u = v.u;
    return (unsigned short)((u + 0x7fffu + ((u >> 16) & 1u)) >> 16);  // RNE
}
__device__ __forceinline__ float bf2f(unsigned short b) {
    union { unsigned int u; float f; } v; v.u = ((unsigned int)b) << 16;
    return v.f;
}

__device__ __forceinline__ float fsig(float x) {
    return 1.f / (1.f + __expf(-x));
}
__device__ __forceinline__ float ftanh(float x) {
    // 1 - 2/(1+e^{2x}); saturates correctly at +/-inf
    return 1.f - 2.f / (1.f + __expf(2.f * x));
}

// ---------------- pack kernels (fp32 -> bf16, with K padding) ----------------

__global__ void pack_x_kernel(const float* __restrict__ x, unsigned short* __restrict__ xp,
                              int M, int K, int Kp) {
    int total = M * Kp;
    for (int idx = blockIdx.x * blockDim.x + threadIdx.x; idx < total;
         idx += gridDim.x * blockDim.x) {
        int r = idx / Kp, k = idx - r * Kp;
        xp[idx] = (k < K) ? f2bf(x[(size_t)r * K + k]) : (unsigned short)0;
    }
}

__global__ void pack_w_kernel(const float* __restrict__ Wf, const float* __restrict__ Wi,
                              const float* __restrict__ Wo, const float* __restrict__ Wc,
                              unsigned short* __restrict__ out, int K, int Kp) {
    int total = 2048 * Kp;
    for (int idx = blockIdx.x * blockDim.x + threadIdx.x; idx < total;
         idx += gridDim.x * blockDim.x) {
        int n = idx / Kp, k = idx - n * Kp;
        int gate = n >> 9, j = n & 511;
        const float* W = (gate == 0) ? Wf : (gate == 1) ? Wi : (gate == 2) ? Wo : Wc;
        out[idx] = (k < K) ? f2bf(W[(size_t)j * K + k]) : (unsigned short)0;
    }
}

// ---------------- gate GEMM (unchanged from round 1, validated) ----------------

__global__ __launch_bounds__(256) void gemm_gates(
    const unsigned short* __restrict__ A, const unsigned short* __restrict__ Bm,
    const float* __restrict__ bF, const float* __restrict__ bI,
    const float* __restrict__ bO, const float* __restrict__ bC,
    unsigned short* __restrict__ G, int Kp) {
    __shared__ unsigned short Alds[64][32];
    __shared__ unsigned short Blds[64][32];
    const int tid = threadIdx.x;
    const int m0 = blockIdx.x * 64;
    const int n0 = blockIdx.y * 64;
    const int w = tid >> 6, l = tid & 63;
    const int lr = l & 15, lk = (l >> 4) * 8;
    const int ldrow = tid >> 2;
    const int ldk = (tid & 3) * 8;
    const unsigned short* Aptr = A + (size_t)(m0 + ldrow) * Kp + ldk;
    const unsigned short* Bptr = Bm + (size_t)(n0 + ldrow) * Kp + ldk;

    f32x4 zero = {0.f, 0.f, 0.f, 0.f};
    f32x4 acc0 = zero, acc1 = zero, acc2 = zero, acc3 = zero;

    for (int k0 = 0; k0 < Kp; k0 += 32) {
        *(uint4*)&Alds[ldrow][ldk] = *(const uint4*)(Aptr + k0);
        *(uint4*)&Blds[ldrow][ldk] = *(const uint4*)(Bptr + k0);
        __syncthreads();
        bf16x8 a = *(const bf16x8*)&Alds[w * 16 + lr][lk];
        bf16x8 b0 = *(const bf16x8*)&Blds[0 * 16 + lr][lk];
        bf16x8 b1 = *(const bf16x8*)&Blds[1 * 16 + lr][lk];
        bf16x8 b2 = *(const bf16x8*)&Blds[2 * 16 + lr][lk];
        bf16x8 b3 = *(const bf16x8*)&Blds[3 * 16 + lr][lk];
        acc0 = __builtin_amdgcn_mfma_f32_16x16x32_bf16(a, b0, acc0, 0, 0, 0);
        acc1 = __builtin_amdgcn_mfma_f32_16x16x32_bf16(a, b1, acc1, 0, 0, 0);
        acc2 = __builtin_amdgcn_mfma_f32_16x16x32_bf16(a, b2, acc2, 0, 0, 0);
        acc3 = __builtin_amdgcn_mfma_f32_16x16x32_bf16(a, b3, acc3, 0, 0, 0);
        __syncthreads();
    }
    const int gate = n0 >> 9;
    const float* bias = (gate == 0) ? bF : (gate == 1) ? bI : (gate == 2) ? bO : bC;
    f32x4 accs[4] = {acc0, acc1, acc2, acc3};
#pragma unroll
    for (int c = 0; c < 4; ++c) {
        int col = n0 + c * 16 + lr;
        float bv = bias[col & 511];
#pragma unroll
        for (int r = 0; r < 4; ++r) {
            int row = m0 + w * 16 + (l >> 4) * 4 + r;
            G[(size_t)row * 2048 + col] = f2bf(accs[c][r] + bv);
        }
    }
}

// ---------------- recurrence: 32 wgs x 256 thr, weights in LDS ----------------
// wg owns j-slice [wg*16, wg*16+16) x 4 gates (64 output dims of 2048).
// Local n = jl*4 + gate (so one 16-wide MFMA n-tile holds 4 jl x 4 gates).
// Wave w (0..3) owns n-tile nt=w. M = 32 = 16 fwd batch + 16 bwd batch.
// h exchanged via IF$-scope atomics in MFMA A-fragment layout:
//   h_frag[parity][ (mb*16+kc)*64 + (m&15) + 16*((k&31)>>3) ]*8 + (k&7)  (ushort)
// Per-wave flags (128, each padded to 128 B) replace the barrier.

__device__ __forceinline__ bf16x8 load_h_frag(const unsigned short* hb, int mb, int kc, int l) {
    size_t idx = ((size_t)(mb * 16 + kc) * 64 + l) * 8;
    unsigned long long v0 = __hip_atomic_load((unsigned long long*)(hb + idx),
                                              __ATOMIC_RELAXED, __HIP_MEMORY_SCOPE_AGENT);
    unsigned long long v1 = __hip_atomic_load((unsigned long long*)(hb + idx + 4),
                                              __ATOMIC_RELAXED, __HIP_MEMORY_SCOPE_AGENT);
    union { unsigned long long q[2]; bf16x8 v; } u;
    u.q[0] = v0; u.q[1] = v1;
    return u.v;
}

template <int LAYER>
__global__ __launch_bounds__(256, 1) void lstm_rec2(
    const unsigned short* __restrict__ U,   // [2048][512] bf16 (row n = gate*512+j)
    const unsigned short* __restrict__ G,   // [T*16][2048] bf16 (bias folded in)
    unsigned short* __restrict__ y_bf,      // LAYER==0: [T*16][1024] bf16
    float* __restrict__ y_f32,              // LAYER==1: d_out [T*16][1024] fp32
    unsigned short* __restrict__ h_frag,    // [2][16384] ushort
    unsigned int* __restrict__ flags,       // [128*32] uint
    int T) {
    __shared__ unsigned short wlds[4 * 16 * 64 * 8];  // 64 KB, frag-major

    const int tid = threadIdx.x;
    const int w = tid >> 6;        // wave 0..3 = n-tile
    const int l = tid & 63;
    const int wg = blockIdx.x;     // 0..31
    const int j0 = wg * 16;
    const int g = l & 3;           // gate id (0=f,1=i,2=o,3=c)
    const int q = (l & 15) >> 2;   // quad index within 16
    const int jl = 4 * w + q;      // local j within wg slice (0..15)
    const int m0 = (l >> 4) * 4 + g;  // the (m&15) row this lane stores
    const int mrow = (l >> 4) * 4;    // base row for its 4 C values
    const int colg = g * 512 + j0 + jl;  // G column for this lane
    const int kcw = wg >> 1;          // k-chunk this wg's j-slice lands in
    const int jlq = ((wg & 1) << 4) + jl;  // j & 31
    const int lslot = m0 + 16 * (jlq >> 3);
    const int jb = jlq & 7;

    // ---- stage weight fragments into LDS (frag-major: zero-conflict reads) ----
    for (int e = tid; e < 4096; e += 256) {
        int fl = e >> 6;
        int ll = e & 63;
        int nt = fl >> 4, kc = fl & 15;
        int nl = nt * 16 + (ll & 15);
        int jj = nl >> 2, gg = nl & 3;
        int nglob = gg * 512 + j0 + jj;
        int k = kc * 32 + (ll >> 4) * 8;
        *(uint4*)&wlds[(size_t)e * 8] = *(const uint4*)&U[(size_t)nglob * 512 + k];
    }
    __syncthreads();

    // ---- zero-round: collectively zero h parity 0, signal flag=1 ----
    {
        unsigned int* h0 = (unsigned int*)h_frag;  // 8192 uints = parity 0
        __hip_atomic_store(&h0[wg * 256 + tid], 0u, __ATOMIC_RELAXED,
                           __HIP_MEMORY_SCOPE_AGENT);
        if (l == 0)
            __hip_atomic_store(&flags[(wg * 4 + w) * 32], 1u, __ATOMIC_RELEASE,
                               __HIP_MEMORY_SCOPE_AGENT);
    }

    // ---- G prefetch for step 0 ----
    unsigned short gpf[2][4];
    {
        const unsigned short* gf_ = G + (size_t)(0 * 16 + mrow) * 2048 + colg;
        const unsigned short* gb_ = G + (size_t)((T - 1) * 16 + mrow) * 2048 + colg;
#pragma unroll
        for (int r = 0; r < 4; ++r) {
            gpf[0][r] = gf_[r * 2048];
            gpf[1][r] = gb_[r * 2048];
        }
    }

    float cst[2][4] = {{0.f, 0.f, 0.f, 0.f}, {0.f, 0.f, 0.f, 0.f}};

    for (int s = 0; s < T; ++s) {
        // consume prefetched G, issue next prefetch
        unsigned short gcur[2][4];
#pragma unroll
        for (int r = 0; r < 4; ++r) {
            gcur[0][r] = gpf[0][r];
            gcur[1][r] = gpf[1][r];
        }
        {
            int sn = (s + 1 < T) ? (s + 1) : (T - 1);
            const unsigned short* gf_ = G + (size_t)(sn * 16 + mrow) * 2048 + colg;
            const unsigned short* gb_ = G + (size_t)((T - 1 - sn) * 16 + mrow) * 2048 + colg;
#pragma unroll
            for (int r = 0; r < 4; ++r) {
                gpf[0][r] = gf_[r * 2048];
                gpf[1][r] = gb_[r * 2048];
            }
        }

        // ---- wait for all 128 wave-flags >= s+1 ----
        {
            unsigned tgt = (unsigned)(s + 1);
            unsigned int* f1 = flags + (size_t)l * 32;
            unsigned int* f2 = flags + (size_t)(64 + l) * 32;
            while (true) {
                unsigned a = __hip_atomic_load(f1, __ATOMIC_ACQUIRE, __HIP_MEMORY_SCOPE_AGENT);
                unsigned b = __hip_atomic_load(f2, __ATOMIC_ACQUIRE, __HIP_MEMORY_SCOPE_AGENT);
                if (__all(a >= tgt && b >= tgt)) break;
            }
        }

        // ---- MFMA: (32 x 512) h  x  (512 x 16) U-tile ----
        const unsigned short* hb = h_frag + (size_t)(s & 1) * 16384;
        f32x4 acc0 = {0.f, 0.f, 0.f, 0.f};
        f32x4 acc1 = {0.f, 0.f, 0.f, 0.f};
#pragma unroll
        for (int kc = 0; kc < 16; ++kc) {
            bf16x8 a0 = load_h_frag(hb, 0, kc, l);
            bf16x8 a1 = load_h_frag(hb, 1, kc, l);
            bf16x8 bw = *(const bf16x8*)&wlds[(((size_t)w * 16 + kc) * 64 + l) * 8];
            acc0 = __builtin_amdgcn_mfma_f32_16x16x32_bf16(a0, bw, acc0, 0, 0, 0);
            acc1 = __builtin_amdgcn_mfma_f32_16x16x32_bf16(a1, bw, acc1, 0, 0, 0);
        }

        // ---- gate combine via quad shuffles + pointwise ----
        float hsel[2];
#pragma unroll
        for (int mb = 0; mb < 2; ++mb) {
            f32x4 acc = mb ? acc1 : acc0;
#pragma unroll
            for (int r = 0; r < 4; ++r) {
                float v = acc[r] + bf2f(gcur[mb][r]);
                float x1 = __shfl_xor(v, 1, 64);
                float x2 = __shfl_xor(v, 2, 64);
                float x3 = __shfl_xor(x1, 2, 64);
                bool b0 = (g & 1) != 0, b1 = (g & 2) != 0;
                float gf = b1 ? (b0 ? x3 : x2) : (b0 ? x1 : v);
                float gi = b1 ? (b0 ? x2 : x3) : (b0 ? v : x1);
                float go = b1 ? (b0 ? x1 : v) : (b0 ? x3 : x2);
                float gc = b1 ? (b0 ? v : x1) : (b0 ? x2 : x3);
                float ft = fsig(gf), it = fsig(gi), ot = fsig(go);
                float cn = it * ftanh(gc) + ft * cst[mb][r];
                cst[mb][r] = cn;
                float hn = ot * ftanh(cn);
                if (r == g) hsel[mb] = hn;  // quad lanes hold identical values; keep own row
            }
        }

        // ---- stores: h (bf16, IF$ fragment layout) + y ----
        const int p1 = (s + 1) & 1;
#pragma unroll
        for (int mb = 0; mb < 2; ++mb) {
            unsigned hb16 = (unsigned)f2bf(hsel[mb]);
            unsigned ho = (unsigned)__shfl_xor((int)hb16, 4, 64);
            unsigned word = hb16 | (ho << 16);
            size_t base = (size_t)p1 * 16384 + ((size_t)(mb * 16 + kcw) * 64 + lslot) * 8 + jb;
            int row = (mb ? (T - 1 - s) : s) * 16 + m0;
            int col = mb * 512 + j0 + jl;
            if ((q & 1) == 0) {
                __hip_atomic_store((unsigned int*)(h_frag + base), word, __ATOMIC_RELAXED,
                                   __HIP_MEMORY_SCOPE_AGENT);
                if (LAYER == 0) {
                    *(unsigned int*)&y_bf[(size_t)row * 1024 + col] = word;
                } else {
                    float hof = __shfl_xor(hsel[mb], 4, 64);
                    // note: shfl must be outside divergence; see below
                    float2 fv = make_float2(hsel[mb], hof);
                    *(float2*)&y_f32[(size_t)row * 1024 + col] = fv;
                }
            } else if (LAYER == 1) {
                // keep shuffle uniform: executed via the call below
            }
        }
        // For LAYER==1 the shuffle inside divergent 'if' above is unsafe; redo uniformly:
        if (LAYER == 1) {
            // (the stores above for LAYER==1 were guarded the same way but the shfl
            //  operand hsel is computed on all lanes; to be safe we recompute here
            //  with shuffles outside the predicate)
        }

        // ---- signal completion ----
        if (l == 0)
            __hip_atomic_store(&flags[(wg * 4 + w) * 32], (unsigned)(s + 2), __ATOMIC_RELEASE,
                               __HIP_MEMORY_SCOPE_AGENT);
    }
}

// NOTE on the LAYER==1 shuffle: __shfl_xor inside the 'if ((q&1)==0)' block reads
// from lanes with (q&1)==1 which are inactive there. To avoid relying on that,
// the kernel below is the actual instantiation used: shuffles hoisted out.

template <int LAYER>
__global__ __launch_bounds__(256, 1) void lstm_rec3(
    const unsigned short* __restrict__ U, const unsigned short* __restrict__ G,
    unsigned short* __restrict__ y_bf, float* __restrict__ y_f32,
    unsigned short* __restrict__ h_frag, unsigned int* __restrict__ flags, int T) {
    __shared__ unsigned short wlds[4 * 16 * 64 * 8];

    const int tid = threadIdx.x;
    const int w = tid >> 6;
    const int l = tid & 63;
    const int wg = blockIdx.x;
    const int j0 = wg * 16;
    const int g = l & 3;
    const int q = (l & 15) >> 2;
    const int jl = 4 * w + q;
    const int m0 = (l >> 4) * 4 + g;
    const int mrow = (l >> 4) * 4;
    const int colg = g * 512 + j0 + jl;
    const int kcw = wg >> 1;
    const int jlq = ((wg & 1) << 4) + jl;
    const int lslot = m0 + 16 * (jlq >> 3);
    const int jb = jlq & 7;

    for (int e = tid; e < 4096; e += 256) {
        int fl = e >> 6;
        int ll = e & 63;
        int nt = fl >> 4, kc = fl & 15;
        int nl = nt * 16 + (ll & 15);
        int jj = nl >> 2, gg = nl & 3;
        int nglob = gg * 512 + j0 + jj;
        int k = kc * 32 + (ll >> 4) * 8;
        *(uint4*)&wlds[(size_t)e * 8] = *(const uint4*)&U[(size_t)nglob * 512 + k];
    }
    __syncthreads();

    {
        unsigned int* h0 = (unsigned int*)h_frag;
        __hip_atomic_store(&h0[wg * 256 + tid], 0u, __ATOMIC_RELAXED,
                           __HIP_MEMORY_SCOPE_AGENT);
        if (l == 0)
            __hip_atomic_store(&flags[(wg * 4 + w) * 32], 1u, __ATOMIC_RELEASE,
                               __HIP_MEMORY_SCOPE_AGENT);
    }

    unsigned short gpf[2][4];
    {
        const unsigned short* gf_ = G + (size_t)mrow * 2048 + colg;
        const unsigned short* gb_ = G + (size_t)((T - 1) * 16 + mrow) * 2048 + colg;
#pragma unroll
        for (int r = 0; r < 4; ++r) {
            gpf[0][r] = gf_[r * 2048];
            gpf[1][r] = gb_[r * 2048];
        }
    }

    float cst[2][4] = {{0.f, 0.f, 0.f, 0.f}, {0.f, 0.f, 0.f, 0.f}};

    for (int s = 0; s < T; ++s) {
        unsigned short gcur[2][4];
#pragma unroll
        for (int r = 0; r < 4; ++r) {
            gcur[0][r] = gpf[0][r];
            gcur[1][r] = gpf[1][r];
        }
        {
            int sn = (s + 1 < T) ? (s + 1) : (T - 1);
            const unsigned short* gf_ = G + (size_t)(sn * 16 + mrow) * 2048 + colg;
            const unsigned short* gb_ = G + (size_t)((T - 1 - sn) * 16 + mrow) * 2048 + colg;
#pragma unroll
            for (int r = 0; r < 4; ++r) {
                gpf[0][r] = gf_[r * 2048];
                gpf[1][r] = gb_[r * 2048];
            }
        }

        {
            unsigned tgt = (unsigned)(s + 1);
            unsigned int* f1 = flags + (size_t)l * 32;
            unsigned int* f2 = flags + (size_t)(64 + l) * 32;
            while (true) {
                unsigned a = __hip_atomic_load(f1, __ATOMIC_ACQUIRE, __HIP_MEMORY_SCOPE_AGENT);
                unsigned b = __hip_atomic_load(f2, __ATOMIC_ACQUIRE, __HIP_MEMORY_SCOPE_AGENT);
                if (__all(a >= tgt && b >= tgt)) break;
            }
        }

        const unsigned short* hb = h_frag + (size_t)(s & 1) * 16384;
        f32x4 acc0 = {0.f, 0.f, 0.f, 0.f};
        f32x4 acc1 = {0.f, 0.f, 0.f, 0.f};
#pragma unroll
        for (int kc = 0; kc < 16; ++kc) {
            bf16x8 a0 = load_h_frag(hb, 0, kc, l);
            bf16x8 a1 = load_h_frag(hb, 1, kc, l);
            bf16x8 bw = *(const bf16x8*)&wlds[(((size_t)w * 16 + kc) * 64 + l) * 8];
            acc0 = __builtin_amdgcn_mfma_f32_16x16x32_bf16(a0, bw, acc0, 0, 0, 0);
            acc1 = __builtin_amdgcn_mfma_f32_16x16x32_bf16(a1, bw, acc1, 0, 0, 0);
        }

        float hsel[2];
#pragma unroll
        for (int mb = 0; mb < 2; ++mb) {
            f32x4 acc = mb ? acc1 : acc0;
#pragma unroll
            for (int r = 0; r < 4; ++r) {
                float v = acc[r] + bf2f(gcur[mb][r]);
                float x1 = __shfl_xor(v, 1, 64);
                float x2 = __shfl_xor(v, 2, 64);
                float x3 = __shfl_xor(x1, 2, 64);
                bool b0 = (g & 1) != 0, b1 = (g & 2) != 0;
                float gf = b1 ? (b0 ? x3 : x2) : (b0 ? x1 : v);
                float gi = b1 ? (b0 ? x2 : x3) : (b0 ? v : x1);
                float go = b1 ? (b0 ? x1 : v) : (b0 ? x3 : x2);
                float gc = b1 ? (b0 ? v : x1) : (b0 ? x2 : x3);
                float ft = fsig(gf), it = fsig(gi), ot = fsig(go);
                float cn = it * ftanh(gc) + ft * cst[mb][r];
                cst[mb][r] = cn;
                float hn = ot * ftanh(cn);
                if (r == g) hsel[mb] = hn;
            }
        }

        const int p1 = (s + 1) & 1;
        // shuffles hoisted out of the predicated store (all lanes active here)
        unsigned hw0, hw1;
        float ho0, ho1;
        {
            unsigned b16 = (unsigned)f2bf(hsel[0]);
            unsigned ho = (unsigned)__shfl_xor((int)b16, 4, 64);
            hw0 = b16 | (ho << 16);
            ho0 = __shfl_xor(hsel[0], 4, 64);
            b16 = (unsigned)f2bf(hsel[1]);
            ho = (unsigned)__shfl_xor((int)b16, 4, 64);
            hw1 = b16 | (ho << 16);
            ho1 = __shfl_xor(hsel[1], 4, 64);
        }
        if ((q & 1) == 0) {
#pragma unroll
            for (int mb = 0; mb < 2; ++mb) {
                unsigned word = mb ? hw1 : hw0;
                size_t base =
                    (size_t)p1 * 16384 + ((size_t)(mb * 16 + kcw) * 64 + lslot) * 8 + jb;
                __hip_atomic_store((unsigned int*)(h_frag + base), word, __ATOMIC_RELAXED,
                                   __HIP_MEMORY_SCOPE_AGENT);
                int row = (mb ? (T - 1 - s) : s) * 16 + m0;
                int col = mb * 512 + j0 + jl;
                if (LAYER == 0) {
                    *(unsigned int*)&y_bf[(size_t)row * 1024 + col] = word;
                } else {
                    float2 fv = make_float2(hsel[mb], mb ? ho1 : ho0);
                    *(float2*)&y_f32[(size_t)row * 1024 + col] = fv;
                }
            }
        }

        if (l == 0)
            __hip_atomic_store(&flags[(wg * 4 + w) * 32], (unsigned)(s + 2), __ATOMIC_RELEASE,
                               __HIP_MEMORY_SCOPE_AGENT);
    }
}

// ---------------- host ----------------

extern "C" void kernel_launch(void* const* d_in, const int* in_sizes, int n_in,
                              void* d_out, int out_size, void* d_ws, size_t ws_size,
                              hipStream_t stream) {
    (void)in_sizes; (void)n_in; (void)out_size; (void)ws_size;
    const int T = 1000, M = T * 16;
    const int K0 = 440, K0p = 448, K1 = 1024;

    char* ws = (char*)d_ws;
    size_t off = 0;
    auto alloc = [&](size_t bytes) -> void* {
        void* p = ws + off;
        off += (bytes + 255) & ~(size_t)255;
        return p;
    };
    unsigned short* G  = (unsigned short*)alloc((size_t)M * 2048 * 2);
    unsigned short* xp = (unsigned short*)alloc((size_t)M * K0p * 2);
    unsigned short* W0 = (unsigned short*)alloc((size_t)2048 * K0p * 2);
    unsigned short* W1 = (unsigned short*)alloc((size_t)2048 * K1 * 2);
    unsigned short* U0 = (unsigned short*)alloc((size_t)2048 * 512 * 2);
    unsigned short* U1 = (unsigned short*)alloc((size_t)2048 * 512 * 2);
    unsigned short* y0 = (unsigned short*)alloc((size_t)M * 1024 * 2);
    unsigned short* hf = (unsigned short*)alloc((size_t)2 * 16384 * 2);
    unsigned int* fl0  = (unsigned int*)alloc((size_t)128 * 32 * 4);
    unsigned int* fl1  = (unsigned int*)alloc((size_t)128 * 32 * 4);

    const float* x = (const float*)d_in[0];

    hipMemsetAsync(fl0, 0, 128 * 32 * 4, stream);
    hipMemsetAsync(fl1, 0, 128 * 32 * 4, stream);

    pack_x_kernel<<<2048, 256, 0, stream>>>(x, xp, M, K0, K0p);
    pack_w_kernel<<<1024, 256, 0, stream>>>((const float*)d_in[1], (const float*)d_in[4],
                                            (const float*)d_in[7], (const float*)d_in[10],
                                            W0, K0, K0p);
    pack_w_kernel<<<1024, 256, 0, stream>>>((const float*)d_in[3], (const float*)d_in[6],
                                            (const float*)d_in[9], (const float*)d_in[12],
                                            U0, 512, 512);
    pack_w_kernel<<<1024, 256, 0, stream>>>((const float*)d_in[13], (const float*)d_in[16],
                                            (const float*)d_in[19], (const float*)d_in[22],
                                            W1, K1, K1);
    pack_w_kernel<<<1024, 256, 0, stream>>>((const float*)d_in[15], (const float*)d_in[18],
                                            (const float*)d_in[21], (const float*)d_in[24],
                                            U1, 512, 512);

    dim3 blk(256);
    dim3 g0(M / 64, 2048 / 64);
    gemm_gates<<<g0, blk, 0, stream>>>(xp, W0, (const float*)d_in[2], (const float*)d_in[5],
                                       (const float*)d_in[8], (const float*)d_in[11], G, K0p);
    lstm_rec3<0><<<32, 256, 0, stream>>>(U0, G, y0, nullptr, hf, fl0, T);
    gemm_gates<<<g0, blk, 0, stream>>>(y0, W1, (const float*)d_in[14], (const float*)d_in[17],
                                       (const float*)d_in[20], (const float*)d_in[23], G, K1);
    lstm_rec3<1><<<32, 256, 0, stream>>>(U1, G, nullptr, (float*)d_out, hf, fl1, T);
}

// Round 3
// 9566.386 us; speedup vs baseline: 5.0259x; 2.5666x over previous
//
#include <hip/hip_runtime.h>
#include <hip/hip_bf16.h>
#include <stdint.h>

// Round 3: same structure as round 2 (32-wg MFMA recurrence, LDS weights,
// quad-shuffle gate combine) but ALL cross-wg communication through explicit
// MALL-coherent accesses (global_load/store sc0 sc1) + s_waitcnt vmcnt(0)
// ordering. No acquire/release atomics -> no buffer_inv / buffer_wbl2 in the
// time loop (those were the 12.6us/step cost in round 2).

typedef __attribute__((ext_vector_type(8))) short bf16x8;
typedef __attribute__((ext_vector_type(4))) float f32x4;
typedef __attribute__((ext_vector_type(4))) int i32x4;

__device__ __forceinline__ unsigned short f2bf(float f) {
    union { float f; unsigned int u; } v; v.f = f;
    unsigned int u = v.u;
    return (unsigned short)((u + 0x7fffu + ((u >> 16) & 1u)) >> 16);  // RNE
}
__device__ __forceinline__ float bf2f(unsigned short b) {
    union { unsigned int u; float f; } v; v.u = ((unsigned int)b) << 16;
    return v.f;
}
__device__ __forceinline__ float fsig(float x) { return 1.f / (1.f + __expf(-x)); }
__device__ __forceinline__ float ftanh(float x) { return 1.f - 2.f / (1.f + __expf(2.f * x)); }

// ---- MALL-coherent access helpers (bypass L1+L2 via sc0 sc1) ----

__device__ __forceinline__ unsigned int coh_ld32(const void* p) {
    unsigned int v;
    asm volatile("global_load_dword %0, %1, off sc0 sc1\n\ts_waitcnt vmcnt(0)"
                 : "=v"(v) : "v"(p) : "memory");
    return v;
}
__device__ __forceinline__ void coh_ld128_issue(i32x4& d, const void* p) {
    asm volatile("global_load_dwordx4 %0, %1, off sc0 sc1" : "=&v"(d) : "v"(p) : "memory");
}
__device__ __forceinline__ void coh_st32(void* p, unsigned int v) {
    asm volatile("global_store_dword %0, %1, off sc0 sc1" :: "v"(p), "v"(v) : "memory");
}
__device__ __forceinline__ void vm_drain() {
    asm volatile("s_waitcnt vmcnt(0)" ::: "memory");
}

// ---------------- pack kernels (fp32 -> bf16, with K padding) ----------------

__global__ void pack_x_kernel(const float* __restrict__ x, unsigned short* __restrict__ xp,
                              int M, int K, int Kp) {
    int total = M * Kp;
    for (int idx = blockIdx.x * blockDim.x + threadIdx.x; idx < total;
         idx += gridDim.x * blockDim.x) {
        int r = idx / Kp, k = idx - r * Kp;
        xp[idx] = (k < K) ? f2bf(x[(size_t)r * K + k]) : (unsigned short)0;
    }
}

__global__ void pack_w_kernel(const float* __restrict__ Wf, const float* __restrict__ Wi,
                              const float* __restrict__ Wo, const float* __restrict__ Wc,
                              unsigned short* __restrict__ out, int K, int Kp) {
    int total = 2048 * Kp;
    for (int idx = blockIdx.x * blockDim.x + threadIdx.x; idx < total;
         idx += gridDim.x * blockDim.x) {
        int n = idx / Kp, k = idx - n * Kp;
        int gate = n >> 9, j = n & 511;
        const float* W = (gate == 0) ? Wf : (gate == 1) ? Wi : (gate == 2) ? Wo : Wc;
        out[idx] = (k < K) ? f2bf(W[(size_t)j * K + k]) : (unsigned short)0;
    }
}

// ---------------- gate GEMM (validated round 1/2) ----------------

__global__ __launch_bounds__(256) void gemm_gates(
    const unsigned short* __restrict__ A, const unsigned short* __restrict__ Bm,
    const float* __restrict__ bF, const float* __restrict__ bI,
    const float* __restrict__ bO, const float* __restrict__ bC,
    unsigned short* __restrict__ G, int Kp) {
    __shared__ unsigned short Alds[64][32];
    __shared__ unsigned short Blds[64][32];
    const int tid = threadIdx.x;
    const int m0 = blockIdx.x * 64;
    const int n0 = blockIdx.y * 64;
    const int w = tid >> 6, l = tid & 63;
    const int lr = l & 15, lk = (l >> 4) * 8;
    const int ldrow = tid >> 2;
    const int ldk = (tid & 3) * 8;
    const unsigned short* Aptr = A + (size_t)(m0 + ldrow) * Kp + ldk;
    const unsigned short* Bptr = Bm + (size_t)(n0 + ldrow) * Kp + ldk;

    f32x4 zero = {0.f, 0.f, 0.f, 0.f};
    f32x4 acc0 = zero, acc1 = zero, acc2 = zero, acc3 = zero;

    for (int k0 = 0; k0 < Kp; k0 += 32) {
        *(uint4*)&Alds[ldrow][ldk] = *(const uint4*)(Aptr + k0);
        *(uint4*)&Blds[ldrow][ldk] = *(const uint4*)(Bptr + k0);
        __syncthreads();
        bf16x8 a = *(const bf16x8*)&Alds[w * 16 + lr][lk];
        bf16x8 b0 = *(const bf16x8*)&Blds[0 * 16 + lr][lk];
        bf16x8 b1 = *(const bf16x8*)&Blds[1 * 16 + lr][lk];
        bf16x8 b2 = *(const bf16x8*)&Blds[2 * 16 + lr][lk];
        bf16x8 b3 = *(const bf16x8*)&Blds[3 * 16 + lr][lk];
        acc0 = __builtin_amdgcn_mfma_f32_16x16x32_bf16(a, b0, acc0, 0, 0, 0);
        acc1 = __builtin_amdgcn_mfma_f32_16x16x32_bf16(a, b1, acc1, 0, 0, 0);
        acc2 = __builtin_amdgcn_mfma_f32_16x16x32_bf16(a, b2, acc2, 0, 0, 0);
        acc3 = __builtin_amdgcn_mfma_f32_16x16x32_bf16(a, b3, acc3, 0, 0, 0);
        __syncthreads();
    }
    const int gate = n0 >> 9;
    const float* bias = (gate == 0) ? bF : (gate == 1) ? bI : (gate == 2) ? bO : bC;
    f32x4 accs[4] = {acc0, acc1, acc2, acc3};
#pragma unroll
    for (int c = 0; c < 4; ++c) {
        int col = n0 + c * 16 + lr;
        float bv = bias[col & 511];
#pragma unroll
        for (int r = 0; r < 4; ++r) {
            int row = m0 + w * 16 + (l >> 4) * 4 + r;
            G[(size_t)row * 2048 + col] = f2bf(accs[c][r] + bv);
        }
    }
}

// ---------------- recurrence: 32 wgs x 256 thr, weights in LDS ----------------
// Same mapping as round 2. Sync: one padded flag line per wg (flags[wg*32]),
// wave 0 polls all 32 lines (coh loads), 2 cheap __syncthreads per step.

template <int LAYER>
__global__ __launch_bounds__(256, 1) void lstm_rec4(
    const unsigned short* __restrict__ U, const unsigned short* __restrict__ G,
    unsigned short* __restrict__ y_bf, float* __restrict__ y_f32,
    unsigned short* __restrict__ h_frag, unsigned int* __restrict__ flags, int T) {
    __shared__ unsigned short wlds[4 * 16 * 64 * 8];  // 64 KB

    const int tid = threadIdx.x;
    const int w = tid >> 6;
    const int l = tid & 63;
    const int wg = blockIdx.x;
    const int j0 = wg * 16;
    const int g = l & 3;
    const int q = (l & 15) >> 2;
    const int jl = 4 * w + q;
    const int m0 = (l >> 4) * 4 + g;
    const int mrow = (l >> 4) * 4;
    const int colg = g * 512 + j0 + jl;
    const int kcw = wg >> 1;
    const int jlq = ((wg & 1) << 4) + jl;
    const int lslot = m0 + 16 * (jlq >> 3);
    const int jb = jlq & 7;

    // stage weight fragments into LDS (frag-major)
    for (int e = tid; e < 4096; e += 256) {
        int fl = e >> 6;
        int ll = e & 63;
        int nt = fl >> 4, kc = fl & 15;
        int nl = nt * 16 + (ll & 15);
        int jj = nl >> 2, gg = nl & 3;
        int nglob = gg * 512 + j0 + jj;
        int k = kc * 32 + (ll >> 4) * 8;
        *(uint4*)&wlds[(size_t)e * 8] = *(const uint4*)&U[(size_t)nglob * 512 + k];
    }

    // zero-round: wg zeroes its 1KB slice of h parity 0 (coherent stores)
    {
        unsigned int* h0w = (unsigned int*)h_frag;
        coh_st32(&h0w[wg * 256 + tid], 0u);
        vm_drain();
        __syncthreads();
        if (tid == 0) coh_st32(&flags[wg * 32], 1u);
    }

    // G prefetch for step 0 (plain cached loads; G written by previous kernel)
    unsigned short gpf[2][4];
    {
        const unsigned short* gf_ = G + (size_t)mrow * 2048 + colg;
        const unsigned short* gb_ = G + (size_t)((T - 1) * 16 + mrow) * 2048 + colg;
#pragma unroll
        for (int r = 0; r < 4; ++r) {
            gpf[0][r] = gf_[r * 2048];
            gpf[1][r] = gb_[r * 2048];
        }
    }

    float cst[2][4] = {{0.f, 0.f, 0.f, 0.f}, {0.f, 0.f, 0.f, 0.f}};

    for (int s = 0; s < T; ++s) {
        unsigned short gcur[2][4];
#pragma unroll
        for (int r = 0; r < 4; ++r) {
            gcur[0][r] = gpf[0][r];
            gcur[1][r] = gpf[1][r];
        }
        {
            int sn = (s + 1 < T) ? (s + 1) : (T - 1);
            const unsigned short* gf_ = G + (size_t)(sn * 16 + mrow) * 2048 + colg;
            const unsigned short* gb_ = G + (size_t)((T - 1 - sn) * 16 + mrow) * 2048 + colg;
#pragma unroll
            for (int r = 0; r < 4; ++r) {
                gpf[0][r] = gf_[r * 2048];
                gpf[1][r] = gb_[r * 2048];
            }
        }

        // ---- wait: wave 0 polls 32 per-wg flags at MALL; others park on barrier ----
        if (w == 0) {
            unsigned tgt = (unsigned)(s + 1);
            int guard = 0;
            while (true) {
                unsigned u = 0xFFFFFFFFu;
                if (l < 32) u = coh_ld32(&flags[l * 32]);
                if (__all(u >= tgt) || ++guard > (1 << 14)) break;
            }
        }
        __syncthreads();

        // ---- batched coherent h loads (32 x 16B per lane), single drain ----
        const unsigned short* hb = h_frag + (size_t)(s & 1) * 16384;
        i32x4 ha0[16], ha1[16];
#pragma unroll
        for (int kc = 0; kc < 16; ++kc) {
            coh_ld128_issue(ha0[kc], hb + ((size_t)(0 * 16 + kc) * 64 + l) * 8);
            coh_ld128_issue(ha1[kc], hb + ((size_t)(1 * 16 + kc) * 64 + l) * 8);
        }
        vm_drain();
        __builtin_amdgcn_sched_barrier(0);  // rule 18: keep MFMAs below the drain

        f32x4 acc0 = {0.f, 0.f, 0.f, 0.f};
        f32x4 acc1 = {0.f, 0.f, 0.f, 0.f};
#pragma unroll
        for (int kc = 0; kc < 16; ++kc) {
            union { i32x4 i; bf16x8 v; } c0, c1;
            c0.i = ha0[kc];
            c1.i = ha1[kc];
            bf16x8 bw = *(const bf16x8*)&wlds[(((size_t)w * 16 + kc) * 64 + l) * 8];
            acc0 = __builtin_amdgcn_mfma_f32_16x16x32_bf16(c0.v, bw, acc0, 0, 0, 0);
            acc1 = __builtin_amdgcn_mfma_f32_16x16x32_bf16(c1.v, bw, acc1, 0, 0, 0);
        }

        // ---- gate combine via quad shuffles + pointwise ----
        float hsel[2];
#pragma unroll
        for (int mb = 0; mb < 2; ++mb) {
            f32x4 acc = mb ? acc1 : acc0;
#pragma unroll
            for (int r = 0; r < 4; ++r) {
                float v = acc[r] + bf2f(gcur[mb][r]);
                float x1 = __shfl_xor(v, 1, 64);
                float x2 = __shfl_xor(v, 2, 64);
                float x3 = __shfl_xor(x1, 2, 64);
                bool b0 = (g & 1) != 0, b1 = (g & 2) != 0;
                float gf = b1 ? (b0 ? x3 : x2) : (b0 ? x1 : v);
                float gi = b1 ? (b0 ? x2 : x3) : (b0 ? v : x1);
                float go = b1 ? (b0 ? x1 : v) : (b0 ? x3 : x2);
                float gc = b1 ? (b0 ? v : x1) : (b0 ? x2 : x3);
                float ft = fsig(gf), it = fsig(gi), ot = fsig(go);
                float cn = it * ftanh(gc) + ft * cst[mb][r];
                cst[mb][r] = cn;
                float hn = ot * ftanh(cn);
                if (r == g) hsel[mb] = hn;
            }
        }

        const int p1 = (s + 1) & 1;
        unsigned hw0, hw1;
        float ho0, ho1;
        {
            unsigned b16 = (unsigned)f2bf(hsel[0]);
            unsigned ho = (unsigned)__shfl_xor((int)b16, 4, 64);
            hw0 = b16 | (ho << 16);
            ho0 = __shfl_xor(hsel[0], 4, 64);
            b16 = (unsigned)f2bf(hsel[1]);
            ho = (unsigned)__shfl_xor((int)b16, 4, 64);
            hw1 = b16 | (ho << 16);
            ho1 = __shfl_xor(hsel[1], 4, 64);
        }
        if ((q & 1) == 0) {
#pragma unroll
            for (int mb = 0; mb < 2; ++mb) {
                unsigned word = mb ? hw1 : hw0;
                size_t base =
                    (size_t)p1 * 16384 + ((size_t)(mb * 16 + kcw) * 64 + lslot) * 8 + jb;
                coh_st32(h_frag + base, word);
                int row = (mb ? (T - 1 - s) : s) * 16 + m0;
                int col = mb * 512 + j0 + jl;
                if (LAYER == 0) {
                    *(unsigned int*)&y_bf[(size_t)row * 1024 + col] = word;
                } else {
                    float2 fv = make_float2(hsel[mb], mb ? ho1 : ho0);
                    *(float2*)&y_f32[(size_t)row * 1024 + col] = fv;
                }
            }
        }

        // h stores committed at MALL before flag publish
        vm_drain();
        __syncthreads();
        if (tid == 0) coh_st32(&flags[wg * 32], (unsigned)(s + 2));
    }
}

// ---------------- host ----------------

extern "C" void kernel_launch(void* const* d_in, const int* in_sizes, int n_in,
                              void* d_out, int out_size, void* d_ws, size_t ws_size,
                              hipStream_t stream) {
    (void)in_sizes; (void)n_in; (void)out_size; (void)ws_size;
    const int T = 1000, M = T * 16;
    const int K0 = 440, K0p = 448, K1 = 1024;

    char* ws = (char*)d_ws;
    size_t off = 0;
    auto alloc = [&](size_t bytes) -> void* {
        void* p = ws + off;
        off += (bytes + 255) & ~(size_t)255;
        return p;
    };
    unsigned short* G  = (unsigned short*)alloc((size_t)M * 2048 * 2);
    unsigned short* xp = (unsigned short*)alloc((size_t)M * K0p * 2);
    unsigned short* W0 = (unsigned short*)alloc((size_t)2048 * K0p * 2);
    unsigned short* W1 = (unsigned short*)alloc((size_t)2048 * K1 * 2);
    unsigned short* U0 = (unsigned short*)alloc((size_t)2048 * 512 * 2);
    unsigned short* U1 = (unsigned short*)alloc((size_t)2048 * 512 * 2);
    unsigned short* y0 = (unsigned short*)alloc((size_t)M * 1024 * 2);
    unsigned short* hf = (unsigned short*)alloc((size_t)2 * 16384 * 2);
    unsigned int* fl0  = (unsigned int*)alloc((size_t)32 * 32 * 4);
    unsigned int* fl1  = (unsigned int*)alloc((size_t)32 * 32 * 4);

    const float* x = (const float*)d_in[0];

    hipMemsetAsync(fl0, 0, 32 * 32 * 4, stream);
    hipMemsetAsync(fl1, 0, 32 * 32 * 4, stream);

    pack_x_kernel<<<2048, 256, 0, stream>>>(x, xp, M, K0, K0p);
    pack_w_kernel<<<1024, 256, 0, stream>>>((const float*)d_in[1], (const float*)d_in[4],
                                            (const float*)d_in[7], (const float*)d_in[10],
                                            W0, K0, K0p);
    pack_w_kernel<<<1024, 256, 0, stream>>>((const float*)d_in[3], (const float*)d_in[6],
                                            (const float*)d_in[9], (const float*)d_in[12],
                                            U0, 512, 512);
    pack_w_kernel<<<1024, 256, 0, stream>>>((const float*)d_in[13], (const float*)d_in[16],
                                            (const float*)d_in[19], (const float*)d_in[22],
                                            W1, K1, K1);
    pack_w_kernel<<<1024, 256, 0, stream>>>((const float*)d_in[15], (const float*)d_in[18],
                                            (const float*)d_in[21], (const float*)d_in[24],
                                            U1, 512, 512);

    dim3 blk(256);
    dim3 g0(M / 64, 2048 / 64);
    gemm_gates<<<g0, blk, 0, stream>>>(xp, W0, (const float*)d_in[2], (const float*)d_in[5],
                                       (const float*)d_in[8], (const float*)d_in[11], G, K0p);
    lstm_rec4<0><<<32, 256, 0, stream>>>(U0, G, y0, nullptr, hf, fl0, T);
    gemm_gates<<<g0, blk, 0, stream>>>(y0, W1, (const float*)d_in[14], (const float*)d_in[17],
                                       (const float*)d_in[20], (const float*)d_in[23], G, K1);
    lstm_rec4<1><<<32, 256, 0, stream>>>(U1, G, nullptr, (float*)d_out, hf, fl1, T);
}